// Round 8
// baseline (998.728 us; speedup 1.0000x reference)
//
#include <hip/hip_runtime.h>
#include <hip/hip_bf16.h>

#define DIM    3000
#define HEADS  10
#define CH     300
#define SS     49
#define BATCH  64
#define ODIM   9000          // 3*DIM
#define NN_TOT (BATCH*SS)    // 3136
#define MP     9088          // padded M (71*128)
#define NP     3200          // padded N (25*128)
#define KP     3008          // padded K (94*32)

typedef __attribute__((ext_vector_type(4))) float    f32x4;
typedef __attribute__((ext_vector_type(8))) _Float16 f16x8;
typedef __attribute__((ext_vector_type(4))) _Float16 f16x4;
typedef __attribute__((ext_vector_type(2))) _Float16 f16x2;

#if defined(__has_builtin)
#if __has_builtin(__builtin_amdgcn_fdot2)
#define HAVE_FDOT2 1
#endif
#endif

__device__ __forceinline__ float dot2(f16x2 a, f16x2 b, float c) {
#ifdef HAVE_FDOT2
    return __builtin_amdgcn_fdot2(a, b, c, false);
#else
    return c + (float)a[0] * (float)b[0] + (float)a[1] * (float)b[1];
#endif
}
__device__ __forceinline__ f16x2 u2h(uint u) { return __builtin_bit_cast(f16x2, u); }

// ---------------------------------------------------------------------------
// Convert W (9000x3000 f32) -> Wh (9088x3008 fp16, zero-padded)
// ---------------------------------------------------------------------------
__global__ __launch_bounds__(256) void k_cvt_w(
    const float* __restrict__ W, _Float16* __restrict__ Wh)
{
    int idx = blockIdx.x * 256 + threadIdx.x;
    int o  = idx / (KP / 8);
    int kc = (idx - o * (KP / 8)) * 8;
    if (o >= MP) return;
    _Float16 u[8];
    if (o < ODIM && kc < DIM) {
        const float* wp = W + (size_t)o * DIM + kc;
        float4 a = *(const float4*)(wp);
        float4 b = *(const float4*)(wp + 4);
        u[0] = (_Float16)a.x; u[1] = (_Float16)a.y;
        u[2] = (_Float16)a.z; u[3] = (_Float16)a.w;
        u[4] = (_Float16)b.x; u[5] = (_Float16)b.y;
        u[6] = (_Float16)b.z; u[7] = (_Float16)b.w;
    } else {
        #pragma unroll
        for (int j = 0; j < 8; j++) u[j] = (_Float16)0.f;
    }
    *(uint4*)(Wh + (size_t)o * KP + kc) = *(const uint4*)u;
}

// ---------------------------------------------------------------------------
// Convert+transpose X (64x3000x49 f32) -> Xt (3200x3008 fp16)
// ---------------------------------------------------------------------------
__global__ __launch_bounds__(256) void k_cvt_x(
    const float* __restrict__ X, _Float16* __restrict__ Xt)
{
    __shared__ float t[64][51];
    const int c0 = blockIdx.x * 64;
    const int b  = blockIdx.y;
    if (b == BATCH) {
        for (int i = threadIdx.x; i < 64 * 64; i += 256) {
            int r = i >> 6, cc = i & 63;
            Xt[(size_t)(NN_TOT + r) * KP + c0 + cc] = (_Float16)0.f;
        }
        return;
    }
    const float* xp = X + (size_t)b * DIM * SS;
    for (int i = threadIdx.x; i < 64 * SS; i += 256) {
        int ci = i / SS, s = i - ci * SS;
        int c = c0 + ci;
        t[ci][s] = (c < DIM) ? xp[(size_t)c * SS + s] : 0.f;
    }
    __syncthreads();
    for (int i = threadIdx.x; i < SS * 64; i += 256) {
        int s = i >> 6, ci = i & 63;
        Xt[(size_t)(b * SS + s) * KP + c0 + ci] = (_Float16)t[ci][s];
    }
}

// ---------------------------------------------------------------------------
// fp16 MFMA GEMM (m97 structure). Grid is (N-tiles, M-tiles): blockIdx.x
// walks N fastest so B (19.3 MB) stays L3-resident and A streams ONCE.
// ---------------------------------------------------------------------------
#define GLL16(gp, lp) __builtin_amdgcn_global_load_lds( \
    (const __attribute__((address_space(1))) void*)(gp), \
    (__attribute__((address_space(3))) void*)(lp), 16, 0, 0)

__global__ __launch_bounds__(256, 3) void k_qkv_mfma(
    const _Float16* __restrict__ Wh, const _Float16* __restrict__ Xt,
    const float* __restrict__ bqkv, _Float16* __restrict__ qkv)
{
    __shared__ _Float16 As[128 * 32];
    __shared__ _Float16 Bs[128 * 32];
    const int tid  = threadIdx.x;
    const int wv   = tid >> 6, lane = tid & 63;
    const int wm   = wv >> 1,  wn   = wv & 1;
    const int m0 = blockIdx.y * 128, n0 = blockIdx.x * 128;   // N-fastest

    f32x4 acc[4][4] = {};

    const int srow  = wv * 32 + (lane >> 2);
    const int skoff = (lane & 3) * 8;
    const size_t ga = (size_t)(m0 + srow) * KP + skoff;
    const size_t gb = (size_t)(n0 + srow) * KP + skoff;
    _Float16* ldsA = As + (wv * 32) * 32;
    _Float16* ldsB = Bs + (wv * 32) * 32;

    const int ar = lane & 15;
    const int kg = (lane >> 4) * 8;

    for (int kt = 0; kt < KP; kt += 32) {
        GLL16(Wh + ga + kt,            ldsA);
        GLL16(Wh + ga + kt + 16 * KP,  ldsA + 16 * 32);
        GLL16(Xt + gb + kt,            ldsB);
        GLL16(Xt + gb + kt + 16 * KP,  ldsB + 16 * 32);
        __syncthreads();
        f16x8 af[4], bfr[4];
        #pragma unroll
        for (int i = 0; i < 4; i++)
            af[i] = *(const f16x8*)(As + (wm * 64 + i * 16 + ar) * 32 + kg);
        #pragma unroll
        for (int j = 0; j < 4; j++)
            bfr[j] = *(const f16x8*)(Bs + (wn * 64 + j * 16 + ar) * 32 + kg);
        #pragma unroll
        for (int i = 0; i < 4; i++)
            #pragma unroll
            for (int j = 0; j < 4; j++)
                acc[i][j] = __builtin_amdgcn_mfma_f32_16x16x32_f16(
                    af[i], bfr[j], acc[i][j], 0, 0, 0);
        __syncthreads();
    }

    const int cr = lane >> 4;
    const int cc = lane & 15;
    #pragma unroll
    for (int j = 0; j < 4; j++) {
        int n = n0 + wn * 64 + j * 16 + cc;
        if (n >= NN_TOT) continue;
        int b = n / SS, s = n - b * SS;
        size_t outb = (size_t)b * ODIM * SS + s;
        #pragma unroll
        for (int i = 0; i < 4; i++) {
            int obase = m0 + wm * 64 + i * 16 + cr * 4;
            f32x4 v = acc[i][j];
            #pragma unroll
            for (int r = 0; r < 4; r++) {
                int o = obase + r;
                if (o < ODIM)
                    qkv[outb + (size_t)o * SS] = (_Float16)(v[r] + bqkv[o]);
            }
        }
    }
}

// ---------------------------------------------------------------------------
// Depthwise 3x3 + bias, then L2-normalize q/k rows. In-place on fp16 qkv.
// ---------------------------------------------------------------------------
__global__ __launch_bounds__(256) void k_dwconv(
    const float* __restrict__ wdw, const float* __restrict__ bdw,
    _Float16* __restrict__ qkv)
{
    __shared__ float sh[4][64];
    const int lane = threadIdx.x & 63;
    const int grp  = threadIdx.x >> 6;
    const int o = blockIdx.x * 4 + grp;
    const int b = blockIdx.y;
    _Float16* p = qkv + ((size_t)b * ODIM + o) * SS;
    float vin = (lane < SS) ? (float)p[lane] : 0.f;
    sh[grp][lane] = vin;
    __syncthreads();

    float outv = bdw[o];
    if (lane < SS) {
        const int y = lane / 7, x = lane - y * 7;
        const float* w = wdw + o * 9;
        #pragma unroll
        for (int dy = 0; dy < 3; dy++) {
            int yy = y + dy - 1;
            if (yy < 0 || yy > 6) continue;
            #pragma unroll
            for (int dx = 0; dx < 3; dx++) {
                int xx = x + dx - 1;
                if (xx < 0 || xx > 6) continue;
                outv = fmaf(sh[grp][yy * 7 + xx], w[dy * 3 + dx], outv);
            }
        }
    }
    if (o < 2 * DIM) {
        float sq = (lane < SS) ? outv * outv : 0.f;
        #pragma unroll
        for (int off = 32; off > 0; off >>= 1) sq += __shfl_xor(sq, off);
        float scale = 1.f / fmaxf(sqrtf(sq), 1e-12f);
        outv *= scale;
    }
    if (lane < SS) p[lane] = (_Float16)outv;
}

// ---------------------------------------------------------------------------
// MFMA flash attention (unchanged from round 6)
// ---------------------------------------------------------------------------
#define KSTR 72    // K_lds row stride (fp16): [320][72]
#define VSTR 328   // VT row stride: [64][328]
#define PSTR 72    // P row stride per wave: [80][72]

__global__ __launch_bounds__(256, 1) void k_attn_mfma(
    const _Float16* __restrict__ qkv, const float* __restrict__ temp,
    float* __restrict__ xm)
{
    __shared__ _Float16 Klds[320 * KSTR];
    __shared__ _Float16 VT[64 * VSTR];
    __shared__ _Float16 Plds[4 * 80 * PSTR];

    const int tid = threadIdx.x;
    const int wv  = tid >> 6;
    const int lane = tid & 63;
    const int fr = lane & 15;
    const int g  = lane >> 4;
    const int bh = blockIdx.x;
    const int b = bh / HEADS, h = bh - b * HEADS;
    const _Float16* qp = qkv + ((size_t)b * ODIM + h * CH) * SS;
    const _Float16* kp = qkv + ((size_t)b * ODIM + DIM + h * CH) * SS;
    const _Float16* vp = qkv + ((size_t)b * ODIM + 2 * DIM + h * CH) * SS;
    const float tscale = temp[h];

    for (int i = tid; i < 320 * KSTR; i += 256) Klds[i] = (_Float16)0.f;
    for (int i = tid; i < 64 * VSTR; i += 256)  VT[i]   = (_Float16)0.f;
    __syncthreads();
    for (int i = tid; i < CH * SS; i += 256) {
        int d = i / SS, s = i - d * SS;
        Klds[d * KSTR + s] = kp[i];
        VT[s * VSTR + d]   = vp[i];
    }

    f16x8 qf[5][2];
    #pragma unroll
    for (int ci = 0; ci < 5; ci++) {
        int c = wv * 80 + ci * 16 + fr;
        #pragma unroll
        for (int kk = 0; kk < 2; kk++) {
            _Float16 tmp[8];
            #pragma unroll
            for (int e = 0; e < 8; e++) {
                int s = kk * 32 + g * 8 + e;
                tmp[e] = (s < SS && c < CH) ? qp[c * SS + s] : (_Float16)0.f;
            }
            qf[ci][kk] = *(const f16x8*)tmp;
        }
    }
    __syncthreads();

    f32x4 oacc[4][5] = {};
    float lsum[5] = {};
    _Float16* Pw = Plds + wv * (80 * PSTR);

    for (int td = 0; td < 5; td++) {
        const int d0 = td * 64;
        f32x4 sacc[4][5] = {};
        #pragma unroll
        for (int kk = 0; kk < 2; kk++) {
            f16x8 af[4];
            #pragma unroll
            for (int di = 0; di < 4; di++)
                af[di] = *(const f16x8*)(Klds + (d0 + di * 16 + fr) * KSTR + kk * 32 + g * 8);
            #pragma unroll
            for (int di = 0; di < 4; di++)
                #pragma unroll
                for (int ci = 0; ci < 5; ci++)
                    sacc[di][ci] = __builtin_amdgcn_mfma_f32_16x16x32_f16(
                        af[di], qf[ci][kk], sacc[di][ci], 0, 0, 0);
        }
        #pragma unroll
        for (int di = 0; di < 4; di++)
            #pragma unroll
            for (int ci = 0; ci < 5; ci++) {
                f32x4 sv = sacc[di][ci];
                float e0 = __expf(sv[0] * tscale);
                float e1 = __expf(sv[1] * tscale);
                float e2 = __expf(sv[2] * tscale);
                float e3 = __expf(sv[3] * tscale);
                lsum[ci] += (e0 + e1) + (e2 + e3);
                f16x4 pk;
                pk[0] = (_Float16)e0; pk[1] = (_Float16)e1;
                pk[2] = (_Float16)e2; pk[3] = (_Float16)e3;
                *(f16x4*)(Pw + (ci * 16 + fr) * PSTR + di * 16 + g * 4) = pk;
            }
        #pragma unroll
        for (int kk = 0; kk < 2; kk++) {
            f16x8 vf[4], pf[5];
            #pragma unroll
            for (int si = 0; si < 4; si++)
                vf[si] = *(const f16x8*)(VT + (si * 16 + fr) * VSTR + d0 + kk * 32 + g * 8);
            #pragma unroll
            for (int ci = 0; ci < 5; ci++)
                pf[ci] = *(const f16x8*)(Pw + (ci * 16 + fr) * PSTR + kk * 32 + g * 8);
            #pragma unroll
            for (int si = 0; si < 4; si++)
                #pragma unroll
                for (int ci = 0; ci < 5; ci++)
                    oacc[si][ci] = __builtin_amdgcn_mfma_f32_16x16x32_f16(
                        vf[si], pf[ci], oacc[si][ci], 0, 0, 0);
        }
    }

    float lf[5];
    #pragma unroll
    for (int ci = 0; ci < 5; ci++) {
        float v = lsum[ci];
        v += __shfl_xor(v, 16);
        v += __shfl_xor(v, 32);
        lf[ci] = 1.f / (v - 20.f);
    }
    float* xpo = xm + (size_t)bh * (SS * CH);
    #pragma unroll
    for (int ci = 0; ci < 5; ci++) {
        int c = wv * 80 + ci * 16 + fr;
        if (c >= CH) continue;
        #pragma unroll
        for (int si = 0; si < 4; si++) {
            f32x4 ov = oacc[si][ci];
            #pragma unroll
            for (int r = 0; r < 4; r++) {
                int s = si * 16 + g * 4 + r;
                if (s < SS) xpo[s * CH + c] = ov[r] * lf[ci];
            }
        }
    }
}

// ---------------------------------------------------------------------------
// Convert mixer channel-MLP weights to fp16 (padded)
// ---------------------------------------------------------------------------
__global__ __launch_bounds__(256) void k_cvt_mixw(
    const float* __restrict__ wc1, const float* __restrict__ wc2,
    _Float16* __restrict__ wc1T, _Float16* __restrict__ wc2p)
{
    int i = blockIdx.x * 256 + threadIdx.x;
    if (i >= 60 * 304) return;
    int j = i / 304, c = i - j * 304;
    wc1T[i] = (c < CH) ? (_Float16)wc1[c * 60 + j] : (_Float16)0.f;
    wc2p[i] = (c < CH) ? (_Float16)wc2[j * CH + c] : (_Float16)0.f;
}

// ---------------------------------------------------------------------------
// K4 v2: mixer x2 + pooling + sigmoid (unchanged from round 6)
// ---------------------------------------------------------------------------
#define TPAD 308
#define YPAD 304

__device__ __forceinline__ float gelu_f(float v) {
    return 0.5f * v * (1.f + erff(v * 0.70710678118654752f));
}

__global__ __launch_bounds__(1024, 4) void k_mixer(
    const float* __restrict__ xm,
    const _Float16* __restrict__ wc1T, const _Float16* __restrict__ wc2p,
    const float* __restrict__ g1, const float* __restrict__ be1,
    const float* __restrict__ g2, const float* __restrict__ be2,
    const float* __restrict__ wt1, const float* __restrict__ bt1,
    const float* __restrict__ wt2, const float* __restrict__ bt2,
    const float* __restrict__ bc1, const float* __restrict__ bc2,
    float* __restrict__ outp)
{
    __shared__ float    t[SS][TPAD];
    __shared__ _Float16 yl[50][YPAD];
    __shared__ float    h1s[50][64];
    __shared__ float    htokT[9][YPAD];
    __shared__ float    wtok[940];

    const int tid = threadIdx.x;
    const int bh  = blockIdx.x;
    const float* xp = xm + (size_t)bh * (SS * CH);

    for (int i = tid; i < SS * CH; i += 1024) {
        int s = i / CH;
        t[s][i - s * CH] = xp[i];
    }
    for (int i = tid; i < 7600; i += 1024) ((uint*)yl)[i] = 0u;
    if (tid < 441) wtok[tid] = wt1[tid];
    else if (tid < 450) wtok[tid] = bt1[tid - 441];
    else if (tid < 891) wtok[tid] = wt2[tid - 450];
    else if (tid < 940) wtok[tid] = bt2[tid - 891];
    __syncthreads();

    const int wave = tid >> 6, lane = tid & 63;
    float attA = 0.f, attM = -1e30f;

    auto layer_norm = [&](const float* g, const float* be) {
        for (int s = wave; s < SS; s += 16) {
            float vals[5];
            float sum = 0.f, sumsq = 0.f;
            #pragma unroll
            for (int k = 0; k < 5; k++) {
                int c = lane + k * 64;
                float v = (c < CH) ? t[s][c] : 0.f;
                vals[k] = v; sum += v; sumsq += v * v;
            }
            #pragma unroll
            for (int off = 32; off > 0; off >>= 1) {
                sum += __shfl_xor(sum, off);
                sumsq += __shfl_xor(sumsq, off);
            }
            float mean = sum * (1.f / 300.f);
            float var  = sumsq * (1.f / 300.f) - mean * mean;
            float inv  = 1.f / sqrtf(var + 1e-5f);
            #pragma unroll
            for (int k = 0; k < 5; k++) {
                int c = lane + k * 64;
                if (c < CH)
                    yl[s][c] = (_Float16)((vals[k] - mean) * inv * g[c] + be[c]);
            }
        }
        __syncthreads();
    };

    for (int pass = 0; pass < 2; pass++) {
        layer_norm(g1, be1);

        if (tid < 76 * 9) {
            int c4 = tid / 9, j = tid - c4 * 9;
            float acc[4] = {0.f, 0.f, 0.f, 0.f};
            #pragma unroll 7
            for (int s = 0; s < SS; s++) {
                float w = wtok[s * 9 + j];
                uint2 ua = *(const uint2*)(&yl[s][c4 * 4]);
                f16x2 p0 = u2h(ua.x), p1 = u2h(ua.y);
                acc[0] = fmaf((float)p0[0], w, acc[0]);
                acc[1] = fmaf((float)p0[1], w, acc[1]);
                acc[2] = fmaf((float)p1[0], w, acc[2]);
                acc[3] = fmaf((float)p1[1], w, acc[3]);
            }
            float bj = wtok[441 + j];
            #pragma unroll
            for (int e = 0; e < 4; e++)
                htokT[j][c4 * 4 + e] = gelu_f(acc[e] + bj);
        }
        __syncthreads();

        for (int it = tid; it < SS * 38; it += 1024) {
            int s = it / 38, c8 = it - s * 38;
            float acc[8];
            float b2v = wtok[891 + s];
            #pragma unroll
            for (int e = 0; e < 8; e++) acc[e] = b2v;
            #pragma unroll
            for (int j = 0; j < 9; j++) {
                float w = wtok[450 + j * SS + s];
                const float* hr = &htokT[j][c8 * 8];
                f32x4 h0 = *(const f32x4*)hr;
                f32x4 h1 = *(const f32x4*)(hr + 4);
                acc[0] = fmaf(h0[0], w, acc[0]); acc[1] = fmaf(h0[1], w, acc[1]);
                acc[2] = fmaf(h0[2], w, acc[2]); acc[3] = fmaf(h0[3], w, acc[3]);
                acc[4] = fmaf(h1[0], w, acc[4]); acc[5] = fmaf(h1[1], w, acc[5]);
                acc[6] = fmaf(h1[2], w, acc[6]); acc[7] = fmaf(h1[3], w, acc[7]);
            }
            #pragma unroll
            for (int e = 0; e < 8; e++) {
                int c = c8 * 8 + e;
                if (c < CH) t[s][c] += acc[e];
            }
        }
        __syncthreads();

        layer_norm(g2, be2);

        if (tid < 25 * 30) {
            int sp = tid / 30, jp = tid - sp * 30;
            int s0 = 2 * sp, s1 = s0 + 1;
            int j0 = 2 * jp, j1 = j0 + 1;
            float a00 = 0.f, a01 = 0.f, a10 = 0.f, a11 = 0.f;
            const uint4* ga0 = (const uint4*)(wc1T + j0 * YPAD);
            const uint4* ga1 = (const uint4*)(wc1T + j1 * YPAD);
            const uint4* y0  = (const uint4*)(&yl[s0][0]);
            const uint4* y1  = (const uint4*)(&yl[s1][0]);
            for (int k = 0; k < 38; k++) {
                uint4 uy0 = y0[k], uy1 = y1[k];
                uint4 uw0 = ga0[k], uw1 = ga1[k];
                a00 = dot2(u2h(uy0.x), u2h(uw0.x), a00);
                a00 = dot2(u2h(uy0.y), u2h(uw0.y), a00);
                a00 = dot2(u2h(uy0.z), u2h(uw0.z), a00);
                a00 = dot2(u2h(uy0.w), u2h(uw0.w), a00);
                a01 = dot2(u2h(uy0.x), u2h(uw1.x), a01);
                a01 = dot2(u2h(uy0.y), u2h(uw1.y), a01);
                a01 = dot2(u2h(uy0.z), u2h(uw1.z), a01);
                a01 = dot2(u2h(uy0.w), u2h(uw1.w), a01);
                a10 = dot2(u2h(uy1.x), u2h(uw0.x), a10);
                a10 = dot2(u2h(uy1.y), u2h(uw0.y), a10);
                a10 = dot2(u2h(uy1.z), u2h(uw0.z), a10);
                a10 = dot2(u2h(uy1.w), u2h(uw0.w), a10);
                a11 = dot2(u2h(uy1.x), u2h(uw1.x), a11);
                a11 = dot2(u2h(uy1.y), u2h(uw1.y), a11);
                a11 = dot2(u2h(uy1.z), u2h(uw1.z), a11);
                a11 = dot2(u2h(uy1.w), u2h(uw1.w), a11);
            }
            float b0 = bc1[j0], b1 = bc1[j1];
            h1s[s0][j0] = gelu_f(a00 + b0);
            h1s[s0][j1] = gelu_f(a01 + b1);
            h1s[s1][j0] = gelu_f(a10 + b0);
            h1s[s1][j1] = gelu_f(a11 + b1);
        }
        __syncthreads();

        if (tid < 25 * 38) {
            int sp = tid / 38, c8 = tid - sp * 38;
            int s0 = 2 * sp, s1 = s0 + 1;
            float acc0[8] = {}, acc1[8] = {};
            const uint4* gw = (const uint4*)(wc2p + c8 * 8);
            #pragma unroll 4
            for (int j = 0; j < 60; j++) {
                float h0 = h1s[s0][j], h1 = h1s[s1][j];
                uint4 uw = gw[j * (YPAD / 8)];
                f16x2 w0 = u2h(uw.x), w1 = u2h(uw.y), w2 = u2h(uw.z), w3 = u2h(uw.w);
                float wf[8] = {(float)w0[0], (float)w0[1], (float)w1[0], (float)w1[1],
                               (float)w2[0], (float)w2[1], (float)w3[0], (float)w3[1]};
                #pragma unroll
                for (int e = 0; e < 8; e++) {
                    acc0[e] = fmaf(h0, wf[e], acc0[e]);
                    acc1[e] = fmaf(h1, wf[e], acc1[e]);
                }
            }
            #pragma unroll
            for (int e = 0; e < 8; e++) {
                int c = c8 * 8 + e;
                if (c < CH) {
                    float bv = bc2[c];
                    t[s0][c] += acc0[e] + bv;
                    if (s1 < SS) t[s1][c] += acc1[e] + bv;
                }
            }
        }
        __syncthreads();

        if (tid < CH) {
            if (pass == 0) {
                float a = 0.f;
                for (int s = 0; s < SS; s++) a += t[s][tid];
                attA = a * (1.f / 49.f);
            } else {
                float m = -1e30f;
                for (int s = 0; s < SS; s++) m = fmaxf(m, t[s][tid]);
                attM = m;
            }
        }
        __syncthreads();
    }

    if (tid < CH)
        outp[(size_t)bh * CH + tid] = 1.f / (1.f + __expf(-(attA + attM)));
}

// ---------------------------------------------------------------------------
extern "C" void kernel_launch(void* const* d_in, const int* in_sizes, int n_in,
                              void* d_out, int out_size, void* d_ws, size_t ws_size,
                              hipStream_t stream)
{
    const float* x     = (const float*)d_in[0];
    const float* temp  = (const float*)d_in[1];
    const float* w_qkv = (const float*)d_in[2];
    const float* b_qkv = (const float*)d_in[3];
    const float* w_dw  = (const float*)d_in[4];
    const float* b_dw  = (const float*)d_in[5];
    const float* g1    = (const float*)d_in[6];
    const float* b1    = (const float*)d_in[7];
    const float* g2    = (const float*)d_in[8];
    const float* b2    = (const float*)d_in[9];
    const float* wt1   = (const float*)d_in[10];
    const float* bt1   = (const float*)d_in[11];
    const float* wt2   = (const float*)d_in[12];
    const float* bt2   = (const float*)d_in[13];
    const float* wc1   = (const float*)d_in[14];
    const float* bc1   = (const float*)d_in[15];
    const float* wc2   = (const float*)d_in[16];
    const float* bc2   = (const float*)d_in[17];

    // workspace layout (bytes):
    //   [0, 56448000)                qkv fp16 [64][9000][49]
    //   [56448000, 111121408)        Wh fp16 (dead after GEMM)
    //   [111121408, 130372608)       Xt fp16 (dead after GEMM)
    //   [56448000, 94080000)         xm f32 [640][49][300]  (aliases Wh)
    //   [111121408, +73KB)           wc1T/wc2p fp16 (aliases Xt)
    _Float16* qkvh = (_Float16*)d_ws;
    _Float16* Wh   = (_Float16*)((char*)d_ws + 56448000);
    _Float16* Xt   = (_Float16*)((char*)d_ws + 111121408);
    float*    xm   = (float*)((char*)d_ws + 56448000);
    _Float16* wc1T = (_Float16*)((char*)d_ws + 111121408);
    _Float16* wc2p = wc1T + 60 * YPAD;
    float*    outp = (float*)d_out;

    k_cvt_w<<<(MP * (KP / 8)) / 256, 256, 0, stream>>>(w_qkv, Wh);
    k_cvt_x<<<dim3(KP / 64, BATCH + 1), 256, 0, stream>>>(x, Xt);

    // N-tiles in x (fastest) so B stays cache-hot and A streams once.
    k_qkv_mfma<<<dim3(NP / 128, MP / 128), 256, 0, stream>>>(Wh, Xt, b_qkv, qkvh);

    k_cvt_mixw<<<(60 * 304 + 255) / 256, 256, 0, stream>>>(wc1, wc2, wc1T, wc2p);

    k_dwconv<<<dim3(ODIM / 4, BATCH), 256, 0, stream>>>(w_dw, b_dw, qkvh);

    k_attn_mfma<<<BATCH * HEADS, 256, 0, stream>>>(qkvh, temp, xm);

    k_mixer<<<BATCH * HEADS, 1024, 0, stream>>>(xm, wc1T, wc2p,
                                                g1, b1, g2, b2,
                                                wt1, bt1, wt2, bt2,
                                                bc1, bc2, outp);
}

// Round 9
// 947.714 us; speedup vs baseline: 1.0538x; 1.0538x over previous
//
#include <hip/hip_runtime.h>
#include <hip/hip_bf16.h>

#define DIM    3000
#define HEADS  10
#define CH     300
#define SS     49
#define BATCH  64
#define ODIM   9000          // 3*DIM
#define NN_TOT (BATCH*SS)    // 3136
#define MP     9088          // padded M (71*128)
#define NP     3200          // padded N (25*128)
#define KP     3008          // padded K (94*32)
#define NWG    1775          // 71*25 GEMM blocks

typedef __attribute__((ext_vector_type(4))) float    f32x4;
typedef __attribute__((ext_vector_type(8))) _Float16 f16x8;
typedef __attribute__((ext_vector_type(4))) _Float16 f16x4;
typedef __attribute__((ext_vector_type(2))) _Float16 f16x2;

#if defined(__has_builtin)
#if __has_builtin(__builtin_amdgcn_fdot2)
#define HAVE_FDOT2 1
#endif
#endif

__device__ __forceinline__ float dot2(f16x2 a, f16x2 b, float c) {
#ifdef HAVE_FDOT2
    return __builtin_amdgcn_fdot2(a, b, c, false);
#else
    return c + (float)a[0] * (float)b[0] + (float)a[1] * (float)b[1];
#endif
}
__device__ __forceinline__ f16x2 u2h(uint u) { return __builtin_bit_cast(f16x2, u); }

// ---------------------------------------------------------------------------
// Convert W (9000x3000 f32) -> Wh (9088x3008 fp16, zero-padded)
// ---------------------------------------------------------------------------
__global__ __launch_bounds__(256) void k_cvt_w(
    const float* __restrict__ W, _Float16* __restrict__ Wh)
{
    int idx = blockIdx.x * 256 + threadIdx.x;
    int o  = idx / (KP / 8);
    int kc = (idx - o * (KP / 8)) * 8;
    if (o >= MP) return;
    _Float16 u[8];
    if (o < ODIM && kc < DIM) {
        const float* wp = W + (size_t)o * DIM + kc;
        float4 a = *(const float4*)(wp);
        float4 b = *(const float4*)(wp + 4);
        u[0] = (_Float16)a.x; u[1] = (_Float16)a.y;
        u[2] = (_Float16)a.z; u[3] = (_Float16)a.w;
        u[4] = (_Float16)b.x; u[5] = (_Float16)b.y;
        u[6] = (_Float16)b.z; u[7] = (_Float16)b.w;
    } else {
        #pragma unroll
        for (int j = 0; j < 8; j++) u[j] = (_Float16)0.f;
    }
    *(uint4*)(Wh + (size_t)o * KP + kc) = *(const uint4*)u;
}

// ---------------------------------------------------------------------------
// Convert+transpose X (64x3000x49 f32) -> Xt (3200x3008 fp16)
// ---------------------------------------------------------------------------
__global__ __launch_bounds__(256) void k_cvt_x(
    const float* __restrict__ X, _Float16* __restrict__ Xt)
{
    __shared__ float t[64][51];
    const int c0 = blockIdx.x * 64;
    const int b  = blockIdx.y;
    if (b == BATCH) {
        for (int i = threadIdx.x; i < 64 * 64; i += 256) {
            int r = i >> 6, cc = i & 63;
            Xt[(size_t)(NN_TOT + r) * KP + c0 + cc] = (_Float16)0.f;
        }
        return;
    }
    const float* xp = X + (size_t)b * DIM * SS;
    for (int i = threadIdx.x; i < 64 * SS; i += 256) {
        int ci = i / SS, s = i - ci * SS;
        int c = c0 + ci;
        t[ci][s] = (c < DIM) ? xp[(size_t)c * SS + s] : 0.f;
    }
    __syncthreads();
    for (int i = threadIdx.x; i < SS * 64; i += 256) {
        int s = i >> 6, ci = i & 63;
        Xt[(size_t)(b * SS + s) * KP + c0 + ci] = (_Float16)t[ci][s];
    }
}

// ---------------------------------------------------------------------------
// fp16 MFMA GEMM (m97 structure) with XCD-chunked + group-walk swizzle:
// each XCD owns a contiguous work range (bijective, nwg=8*221+7 -> m204
// formula); within it, groups of G=4 M-rows x 25 N-tiles keep a 3.1 MB
// A-panel L2-resident while B streams from L3.
// ---------------------------------------------------------------------------
#define GLL16(gp, lp) __builtin_amdgcn_global_load_lds( \
    (const __attribute__((address_space(1))) void*)(gp), \
    (__attribute__((address_space(3))) void*)(lp), 16, 0, 0)

__global__ __launch_bounds__(256, 3) void k_qkv_mfma(
    const _Float16* __restrict__ Wh, const _Float16* __restrict__ Xt,
    const float* __restrict__ bqkv, _Float16* __restrict__ qkv)
{
    __shared__ _Float16 As[128 * 32];
    __shared__ _Float16 Bs[128 * 32];
    const int tid  = threadIdx.x;
    const int wv   = tid >> 6, lane = tid & 63;
    const int wm   = wv >> 1,  wn   = wv & 1;

    // ---- XCD-chunked bijection: bid -> wid (XCD0..6 own 222, XCD7 owns 221)
    const int bid = blockIdx.x;
    const int xcd = bid & 7;
    const int idx = bid >> 3;
    const int wid = (xcd < 7) ? xcd * 222 + idx : 7 * 222 + idx;
    // ---- group walk: G=4 M-rows per group, M-fastest within group
    int g, rem, gM;
    if (wid < 1700) { g = wid / 100; rem = wid - g * 100; gM = 4; }
    else            { g = 17;        rem = wid - 1700;    gM = 3; }
    const int nt = rem / gM;
    const int mt = g * 4 + (rem - nt * gM);
    const int m0 = mt * 128, n0 = nt * 128;

    f32x4 acc[4][4] = {};

    const int srow  = wv * 32 + (lane >> 2);
    const int skoff = (lane & 3) * 8;
    const size_t ga = (size_t)(m0 + srow) * KP + skoff;
    const size_t gb = (size_t)(n0 + srow) * KP + skoff;
    _Float16* ldsA = As + (wv * 32) * 32;
    _Float16* ldsB = Bs + (wv * 32) * 32;

    const int ar = lane & 15;
    const int kg = (lane >> 4) * 8;

    for (int kt = 0; kt < KP; kt += 32) {
        GLL16(Wh + ga + kt,            ldsA);
        GLL16(Wh + ga + kt + 16 * KP,  ldsA + 16 * 32);
        GLL16(Xt + gb + kt,            ldsB);
        GLL16(Xt + gb + kt + 16 * KP,  ldsB + 16 * 32);
        __syncthreads();
        f16x8 af[4], bfr[4];
        #pragma unroll
        for (int i = 0; i < 4; i++)
            af[i] = *(const f16x8*)(As + (wm * 64 + i * 16 + ar) * 32 + kg);
        #pragma unroll
        for (int j = 0; j < 4; j++)
            bfr[j] = *(const f16x8*)(Bs + (wn * 64 + j * 16 + ar) * 32 + kg);
        #pragma unroll
        for (int i = 0; i < 4; i++)
            #pragma unroll
            for (int j = 0; j < 4; j++)
                acc[i][j] = __builtin_amdgcn_mfma_f32_16x16x32_f16(
                    af[i], bfr[j], acc[i][j], 0, 0, 0);
        __syncthreads();
    }

    const int cr = lane >> 4;
    const int cc = lane & 15;
    #pragma unroll
    for (int j = 0; j < 4; j++) {
        int n = n0 + wn * 64 + j * 16 + cc;
        if (n >= NN_TOT) continue;
        int b = n / SS, s = n - b * SS;
        size_t outb = (size_t)b * ODIM * SS + s;
        #pragma unroll
        for (int i = 0; i < 4; i++) {
            int obase = m0 + wm * 64 + i * 16 + cr * 4;
            f32x4 v = acc[i][j];
            #pragma unroll
            for (int r = 0; r < 4; r++) {
                int o = obase + r;
                if (o < ODIM)
                    qkv[outb + (size_t)o * SS] = (_Float16)(v[r] + bqkv[o]);
            }
        }
    }
}

// ---------------------------------------------------------------------------
// Depthwise 3x3 + bias, then L2-normalize q/k rows. In-place on fp16 qkv.
// ---------------------------------------------------------------------------
__global__ __launch_bounds__(256) void k_dwconv(
    const float* __restrict__ wdw, const float* __restrict__ bdw,
    _Float16* __restrict__ qkv)
{
    __shared__ float sh[4][64];
    const int lane = threadIdx.x & 63;
    const int grp  = threadIdx.x >> 6;
    const int o = blockIdx.x * 4 + grp;
    const int b = blockIdx.y;
    _Float16* p = qkv + ((size_t)b * ODIM + o) * SS;
    float vin = (lane < SS) ? (float)p[lane] : 0.f;
    sh[grp][lane] = vin;
    __syncthreads();

    float outv = bdw[o];
    if (lane < SS) {
        const int y = lane / 7, x = lane - y * 7;
        const float* w = wdw + o * 9;
        #pragma unroll
        for (int dy = 0; dy < 3; dy++) {
            int yy = y + dy - 1;
            if (yy < 0 || yy > 6) continue;
            #pragma unroll
            for (int dx = 0; dx < 3; dx++) {
                int xx = x + dx - 1;
                if (xx < 0 || xx > 6) continue;
                outv = fmaf(sh[grp][yy * 7 + xx], w[dy * 3 + dx], outv);
            }
        }
    }
    if (o < 2 * DIM) {
        float sq = (lane < SS) ? outv * outv : 0.f;
        #pragma unroll
        for (int off = 32; off > 0; off >>= 1) sq += __shfl_xor(sq, off);
        float scale = 1.f / fmaxf(sqrtf(sq), 1e-12f);
        outv *= scale;
    }
    if (lane < SS) p[lane] = (_Float16)outv;
}

// ---------------------------------------------------------------------------
// MFMA flash attention (unchanged)
// ---------------------------------------------------------------------------
#define KSTR 72    // K_lds row stride (fp16): [320][72]
#define VSTR 328   // VT row stride: [64][328]
#define PSTR 72    // P row stride per wave: [80][72]

__global__ __launch_bounds__(256, 1) void k_attn_mfma(
    const _Float16* __restrict__ qkv, const float* __restrict__ temp,
    float* __restrict__ xm)
{
    __shared__ _Float16 Klds[320 * KSTR];
    __shared__ _Float16 VT[64 * VSTR];
    __shared__ _Float16 Plds[4 * 80 * PSTR];

    const int tid = threadIdx.x;
    const int wv  = tid >> 6;
    const int lane = tid & 63;
    const int fr = lane & 15;
    const int g  = lane >> 4;
    const int bh = blockIdx.x;
    const int b = bh / HEADS, h = bh - b * HEADS;
    const _Float16* qp = qkv + ((size_t)b * ODIM + h * CH) * SS;
    const _Float16* kp = qkv + ((size_t)b * ODIM + DIM + h * CH) * SS;
    const _Float16* vp = qkv + ((size_t)b * ODIM + 2 * DIM + h * CH) * SS;
    const float tscale = temp[h];

    for (int i = tid; i < 320 * KSTR; i += 256) Klds[i] = (_Float16)0.f;
    for (int i = tid; i < 64 * VSTR; i += 256)  VT[i]   = (_Float16)0.f;
    __syncthreads();
    for (int i = tid; i < CH * SS; i += 256) {
        int d = i / SS, s = i - d * SS;
        Klds[d * KSTR + s] = kp[i];
        VT[s * VSTR + d]   = vp[i];
    }

    f16x8 qf[5][2];
    #pragma unroll
    for (int ci = 0; ci < 5; ci++) {
        int c = wv * 80 + ci * 16 + fr;
        #pragma unroll
        for (int kk = 0; kk < 2; kk++) {
            _Float16 tmp[8];
            #pragma unroll
            for (int e = 0; e < 8; e++) {
                int s = kk * 32 + g * 8 + e;
                tmp[e] = (s < SS && c < CH) ? qp[c * SS + s] : (_Float16)0.f;
            }
            qf[ci][kk] = *(const f16x8*)tmp;
        }
    }
    __syncthreads();

    f32x4 oacc[4][5] = {};
    float lsum[5] = {};
    _Float16* Pw = Plds + wv * (80 * PSTR);

    for (int td = 0; td < 5; td++) {
        const int d0 = td * 64;
        f32x4 sacc[4][5] = {};
        #pragma unroll
        for (int kk = 0; kk < 2; kk++) {
            f16x8 af[4];
            #pragma unroll
            for (int di = 0; di < 4; di++)
                af[di] = *(const f16x8*)(Klds + (d0 + di * 16 + fr) * KSTR + kk * 32 + g * 8);
            #pragma unroll
            for (int di = 0; di < 4; di++)
                #pragma unroll
                for (int ci = 0; ci < 5; ci++)
                    sacc[di][ci] = __builtin_amdgcn_mfma_f32_16x16x32_f16(
                        af[di], qf[ci][kk], sacc[di][ci], 0, 0, 0);
        }
        #pragma unroll
        for (int di = 0; di < 4; di++)
            #pragma unroll
            for (int ci = 0; ci < 5; ci++) {
                f32x4 sv = sacc[di][ci];
                float e0 = __expf(sv[0] * tscale);
                float e1 = __expf(sv[1] * tscale);
                float e2 = __expf(sv[2] * tscale);
                float e3 = __expf(sv[3] * tscale);
                lsum[ci] += (e0 + e1) + (e2 + e3);
                f16x4 pk;
                pk[0] = (_Float16)e0; pk[1] = (_Float16)e1;
                pk[2] = (_Float16)e2; pk[3] = (_Float16)e3;
                *(f16x4*)(Pw + (ci * 16 + fr) * PSTR + di * 16 + g * 4) = pk;
            }
        #pragma unroll
        for (int kk = 0; kk < 2; kk++) {
            f16x8 vf[4], pf[5];
            #pragma unroll
            for (int si = 0; si < 4; si++)
                vf[si] = *(const f16x8*)(VT + (si * 16 + fr) * VSTR + d0 + kk * 32 + g * 8);
            #pragma unroll
            for (int ci = 0; ci < 5; ci++)
                pf[ci] = *(const f16x8*)(Pw + (ci * 16 + fr) * PSTR + kk * 32 + g * 8);
            #pragma unroll
            for (int si = 0; si < 4; si++)
                #pragma unroll
                for (int ci = 0; ci < 5; ci++)
                    oacc[si][ci] = __builtin_amdgcn_mfma_f32_16x16x32_f16(
                        vf[si], pf[ci], oacc[si][ci], 0, 0, 0);
        }
    }

    float lf[5];
    #pragma unroll
    for (int ci = 0; ci < 5; ci++) {
        float v = lsum[ci];
        v += __shfl_xor(v, 16);
        v += __shfl_xor(v, 32);
        lf[ci] = 1.f / (v - 20.f);
    }
    float* xpo = xm + (size_t)bh * (SS * CH);
    #pragma unroll
    for (int ci = 0; ci < 5; ci++) {
        int c = wv * 80 + ci * 16 + fr;
        if (c >= CH) continue;
        #pragma unroll
        for (int si = 0; si < 4; si++) {
            f32x4 ov = oacc[si][ci];
            #pragma unroll
            for (int r = 0; r < 4; r++) {
                int s = si * 16 + g * 4 + r;
                if (s < SS) xpo[s * CH + c] = ov[r] * lf[ci];
            }
        }
    }
}

// ---------------------------------------------------------------------------
// Convert mixer channel-MLP weights to fp16 (padded)
// ---------------------------------------------------------------------------
__global__ __launch_bounds__(256) void k_cvt_mixw(
    const float* __restrict__ wc1, const float* __restrict__ wc2,
    _Float16* __restrict__ wc1T, _Float16* __restrict__ wc2p)
{
    int i = blockIdx.x * 256 + threadIdx.x;
    if (i >= 60 * 304) return;
    int j = i / 304, c = i - j * 304;
    wc1T[i] = (c < CH) ? (_Float16)wc1[c * 60 + j] : (_Float16)0.f;
    wc2p[i] = (c < CH) ? (_Float16)wc2[j * CH + c] : (_Float16)0.f;
}

// ---------------------------------------------------------------------------
// K4 v2: mixer x2 + pooling + sigmoid (unchanged)
// ---------------------------------------------------------------------------
#define TPAD 308
#define YPAD 304

__device__ __forceinline__ float gelu_f(float v) {
    return 0.5f * v * (1.f + erff(v * 0.70710678118654752f));
}

__global__ __launch_bounds__(1024, 4) void k_mixer(
    const float* __restrict__ xm,
    const _Float16* __restrict__ wc1T, const _Float16* __restrict__ wc2p,
    const float* __restrict__ g1, const float* __restrict__ be1,
    const float* __restrict__ g2, const float* __restrict__ be2,
    const float* __restrict__ wt1, const float* __restrict__ bt1,
    const float* __restrict__ wt2, const float* __restrict__ bt2,
    const float* __restrict__ bc1, const float* __restrict__ bc2,
    float* __restrict__ outp)
{
    __shared__ float    t[SS][TPAD];
    __shared__ _Float16 yl[50][YPAD];
    __shared__ float    h1s[50][64];
    __shared__ float    htokT[9][YPAD];
    __shared__ float    wtok[940];

    const int tid = threadIdx.x;
    const int bh  = blockIdx.x;
    const float* xp = xm + (size_t)bh * (SS * CH);

    for (int i = tid; i < SS * CH; i += 1024) {
        int s = i / CH;
        t[s][i - s * CH] = xp[i];
    }
    for (int i = tid; i < 7600; i += 1024) ((uint*)yl)[i] = 0u;
    if (tid < 441) wtok[tid] = wt1[tid];
    else if (tid < 450) wtok[tid] = bt1[tid - 441];
    else if (tid < 891) wtok[tid] = wt2[tid - 450];
    else if (tid < 940) wtok[tid] = bt2[tid - 891];
    __syncthreads();

    const int wave = tid >> 6, lane = tid & 63;
    float attA = 0.f, attM = -1e30f;

    auto layer_norm = [&](const float* g, const float* be) {
        for (int s = wave; s < SS; s += 16) {
            float vals[5];
            float sum = 0.f, sumsq = 0.f;
            #pragma unroll
            for (int k = 0; k < 5; k++) {
                int c = lane + k * 64;
                float v = (c < CH) ? t[s][c] : 0.f;
                vals[k] = v; sum += v; sumsq += v * v;
            }
            #pragma unroll
            for (int off = 32; off > 0; off >>= 1) {
                sum += __shfl_xor(sum, off);
                sumsq += __shfl_xor(sumsq, off);
            }
            float mean = sum * (1.f / 300.f);
            float var  = sumsq * (1.f / 300.f) - mean * mean;
            float inv  = 1.f / sqrtf(var + 1e-5f);
            #pragma unroll
            for (int k = 0; k < 5; k++) {
                int c = lane + k * 64;
                if (c < CH)
                    yl[s][c] = (_Float16)((vals[k] - mean) * inv * g[c] + be[c]);
            }
        }
        __syncthreads();
    };

    for (int pass = 0; pass < 2; pass++) {
        layer_norm(g1, be1);

        if (tid < 76 * 9) {
            int c4 = tid / 9, j = tid - c4 * 9;
            float acc[4] = {0.f, 0.f, 0.f, 0.f};
            #pragma unroll 7
            for (int s = 0; s < SS; s++) {
                float w = wtok[s * 9 + j];
                uint2 ua = *(const uint2*)(&yl[s][c4 * 4]);
                f16x2 p0 = u2h(ua.x), p1 = u2h(ua.y);
                acc[0] = fmaf((float)p0[0], w, acc[0]);
                acc[1] = fmaf((float)p0[1], w, acc[1]);
                acc[2] = fmaf((float)p1[0], w, acc[2]);
                acc[3] = fmaf((float)p1[1], w, acc[3]);
            }
            float bj = wtok[441 + j];
            #pragma unroll
            for (int e = 0; e < 4; e++)
                htokT[j][c4 * 4 + e] = gelu_f(acc[e] + bj);
        }
        __syncthreads();

        for (int it = tid; it < SS * 38; it += 1024) {
            int s = it / 38, c8 = it - s * 38;
            float acc[8];
            float b2v = wtok[891 + s];
            #pragma unroll
            for (int e = 0; e < 8; e++) acc[e] = b2v;
            #pragma unroll
            for (int j = 0; j < 9; j++) {
                float w = wtok[450 + j * SS + s];
                const float* hr = &htokT[j][c8 * 8];
                f32x4 h0 = *(const f32x4*)hr;
                f32x4 h1 = *(const f32x4*)(hr + 4);
                acc[0] = fmaf(h0[0], w, acc[0]); acc[1] = fmaf(h0[1], w, acc[1]);
                acc[2] = fmaf(h0[2], w, acc[2]); acc[3] = fmaf(h0[3], w, acc[3]);
                acc[4] = fmaf(h1[0], w, acc[4]); acc[5] = fmaf(h1[1], w, acc[5]);
                acc[6] = fmaf(h1[2], w, acc[6]); acc[7] = fmaf(h1[3], w, acc[7]);
            }
            #pragma unroll
            for (int e = 0; e < 8; e++) {
                int c = c8 * 8 + e;
                if (c < CH) t[s][c] += acc[e];
            }
        }
        __syncthreads();

        layer_norm(g2, be2);

        if (tid < 25 * 30) {
            int sp = tid / 30, jp = tid - sp * 30;
            int s0 = 2 * sp, s1 = s0 + 1;
            int j0 = 2 * jp, j1 = j0 + 1;
            float a00 = 0.f, a01 = 0.f, a10 = 0.f, a11 = 0.f;
            const uint4* ga0 = (const uint4*)(wc1T + j0 * YPAD);
            const uint4* ga1 = (const uint4*)(wc1T + j1 * YPAD);
            const uint4* y0  = (const uint4*)(&yl[s0][0]);
            const uint4* y1  = (const uint4*)(&yl[s1][0]);
            for (int k = 0; k < 38; k++) {
                uint4 uy0 = y0[k], uy1 = y1[k];
                uint4 uw0 = ga0[k], uw1 = ga1[k];
                a00 = dot2(u2h(uy0.x), u2h(uw0.x), a00);
                a00 = dot2(u2h(uy0.y), u2h(uw0.y), a00);
                a00 = dot2(u2h(uy0.z), u2h(uw0.z), a00);
                a00 = dot2(u2h(uy0.w), u2h(uw0.w), a00);
                a01 = dot2(u2h(uy0.x), u2h(uw1.x), a01);
                a01 = dot2(u2h(uy0.y), u2h(uw1.y), a01);
                a01 = dot2(u2h(uy0.z), u2h(uw1.z), a01);
                a01 = dot2(u2h(uy0.w), u2h(uw1.w), a01);
                a10 = dot2(u2h(uy1.x), u2h(uw0.x), a10);
                a10 = dot2(u2h(uy1.y), u2h(uw0.y), a10);
                a10 = dot2(u2h(uy1.z), u2h(uw0.z), a10);
                a10 = dot2(u2h(uy1.w), u2h(uw0.w), a10);
                a11 = dot2(u2h(uy1.x), u2h(uw1.x), a11);
                a11 = dot2(u2h(uy1.y), u2h(uw1.y), a11);
                a11 = dot2(u2h(uy1.z), u2h(uw1.z), a11);
                a11 = dot2(u2h(uy1.w), u2h(uw1.w), a11);
            }
            float b0 = bc1[j0], b1 = bc1[j1];
            h1s[s0][j0] = gelu_f(a00 + b0);
            h1s[s0][j1] = gelu_f(a01 + b1);
            h1s[s1][j0] = gelu_f(a10 + b0);
            h1s[s1][j1] = gelu_f(a11 + b1);
        }
        __syncthreads();

        if (tid < 25 * 38) {
            int sp = tid / 38, c8 = tid - sp * 38;
            int s0 = 2 * sp, s1 = s0 + 1;
            float acc0[8] = {}, acc1[8] = {};
            const uint4* gw = (const uint4*)(wc2p + c8 * 8);
            #pragma unroll 4
            for (int j = 0; j < 60; j++) {
                float h0 = h1s[s0][j], h1 = h1s[s1][j];
                uint4 uw = gw[j * (YPAD / 8)];
                f16x2 w0 = u2h(uw.x), w1 = u2h(uw.y), w2 = u2h(uw.z), w3 = u2h(uw.w);
                float wf[8] = {(float)w0[0], (float)w0[1], (float)w1[0], (float)w1[1],
                               (float)w2[0], (float)w2[1], (float)w3[0], (float)w3[1]};
                #pragma unroll
                for (int e = 0; e < 8; e++) {
                    acc0[e] = fmaf(h0, wf[e], acc0[e]);
                    acc1[e] = fmaf(h1, wf[e], acc1[e]);
                }
            }
            #pragma unroll
            for (int e = 0; e < 8; e++) {
                int c = c8 * 8 + e;
                if (c < CH) {
                    float bv = bc2[c];
                    t[s0][c] += acc0[e] + bv;
                    if (s1 < SS) t[s1][c] += acc1[e] + bv;
                }
            }
        }
        __syncthreads();

        if (tid < CH) {
            if (pass == 0) {
                float a = 0.f;
                for (int s = 0; s < SS; s++) a += t[s][tid];
                attA = a * (1.f / 49.f);
            } else {
                float m = -1e30f;
                for (int s = 0; s < SS; s++) m = fmaxf(m, t[s][tid]);
                attM = m;
            }
        }
        __syncthreads();
    }

    if (tid < CH)
        outp[(size_t)bh * CH + tid] = 1.f / (1.f + __expf(-(attA + attM)));
}

// ---------------------------------------------------------------------------
extern "C" void kernel_launch(void* const* d_in, const int* in_sizes, int n_in,
                              void* d_out, int out_size, void* d_ws, size_t ws_size,
                              hipStream_t stream)
{
    const float* x     = (const float*)d_in[0];
    const float* temp  = (const float*)d_in[1];
    const float* w_qkv = (const float*)d_in[2];
    const float* b_qkv = (const float*)d_in[3];
    const float* w_dw  = (const float*)d_in[4];
    const float* b_dw  = (const float*)d_in[5];
    const float* g1    = (const float*)d_in[6];
    const float* b1    = (const float*)d_in[7];
    const float* g2    = (const float*)d_in[8];
    const float* b2    = (const float*)d_in[9];
    const float* wt1   = (const float*)d_in[10];
    const float* bt1   = (const float*)d_in[11];
    const float* wt2   = (const float*)d_in[12];
    const float* bt2   = (const float*)d_in[13];
    const float* wc1   = (const float*)d_in[14];
    const float* bc1   = (const float*)d_in[15];
    const float* wc2   = (const float*)d_in[16];
    const float* bc2   = (const float*)d_in[17];

    // workspace layout (bytes):
    //   [0, 56448000)                qkv fp16 [64][9000][49]
    //   [56448000, 111121408)        Wh fp16 (dead after GEMM)
    //   [111121408, 130372608)       Xt fp16 (dead after GEMM)
    //   [56448000, 94080000)         xm f32 [640][49][300]  (aliases Wh)
    //   [111121408, +73KB)           wc1T/wc2p fp16 (aliases Xt)
    _Float16* qkvh = (_Float16*)d_ws;
    _Float16* Wh   = (_Float16*)((char*)d_ws + 56448000);
    _Float16* Xt   = (_Float16*)((char*)d_ws + 111121408);
    float*    xm   = (float*)((char*)d_ws + 56448000);
    _Float16* wc1T = (_Float16*)((char*)d_ws + 111121408);
    _Float16* wc2p = wc1T + 60 * YPAD;
    float*    outp = (float*)d_out;

    k_cvt_w<<<(MP * (KP / 8)) / 256, 256, 0, stream>>>(w_qkv, Wh);
    k_cvt_x<<<dim3(KP / 64, BATCH + 1), 256, 0, stream>>>(x, Xt);

    // 1D grid; block->tile mapping is the XCD-chunked group-walk bijection.
    k_qkv_mfma<<<NWG, 256, 0, stream>>>(Wh, Xt, b_qkv, qkvh);

    k_cvt_mixw<<<(60 * 304 + 255) / 256, 256, 0, stream>>>(wc1, wc2, wc1T, wc2p);

    k_dwconv<<<dim3(ODIM / 4, BATCH), 256, 0, stream>>>(w_dw, b_dw, qkvh);

    k_attn_mfma<<<BATCH * HEADS, 256, 0, stream>>>(qkvh, temp, xm);

    k_mixer<<<BATCH * HEADS, 1024, 0, stream>>>(xm, wc1T, wc2p,
                                                g1, b1, g2, b2,
                                                wt1, bt1, wt2, bt2,
                                                bc1, bc2, outp);
}